// Round 5
// baseline (246.636 us; speedup 1.0000x reference)
//
#include <hip/hip_runtime.h>
#include <math.h>

#define B_   8
#define S_   1024
#define NXc  768
#define H_   12
#define HDc  64
#define M_   (B_*S_)        // 8192
#define NQKV (3*NXc)        // 2304

typedef __attribute__((ext_vector_type(8))) short short8;
typedef __attribute__((ext_vector_type(4))) float f32x4;

__device__ inline unsigned short f2bf(float f) {
  unsigned u = __float_as_uint(f);
  return (unsigned short)((u + 0x7fffu + ((u >> 16) & 1u)) >> 16);
}
__device__ inline float bf2f(unsigned short h) {
  return __uint_as_float(((unsigned)h) << 16);
}

// ---- workspace layout (floats) ----
static const size_t UA_OFF_F  = 0;                                   // bf16 Ut attn [NQKV][NXc]
static const size_t UA_F_CNT  = ((size_t)NQKV * NXc + 1) / 2;        // 884736
static const size_t UP_OFF_F  = UA_OFF_F + UA_F_CNT;                 // bf16 Ut proj [NXc][NXc]
static const size_t UP_F_CNT  = ((size_t)NXc * NXc + 1) / 2;         // 294912
static const size_t QBF_OFF_F = UP_OFF_F + UP_F_CNT;                 // bf16 int q [B,H,S,64]
static const size_t HALF_CNT  = ((size_t)M_ * NXc + 1) / 2;          // 3145728
static const size_t KBF_OFF_F = QBF_OFF_F + HALF_CNT;                // bf16 int k [B,H,S,64]
static const size_t VBT_OFF_F = KBF_OFF_F + HALF_CNT;                // bf16 int v^T [B,H,64,S]
static const size_t ABF_OFF_F = VBT_OFF_F + HALF_CNT;                // bf16 attn out [B,S,NX]
                                                                     // (ALSO: xhi before attn)
static const size_t SC_OFF    = ABF_OFF_F + HALF_CNT;
static const size_t WS_FLOATS_NEEDED = SC_OFF + 2;                   // ~13.8M floats (55MB)

// ---------------- max |tanh(w)| reduction, both weights in one launch --------
__global__ void k_maxtanh2(const float* __restrict__ wa, const float* __restrict__ wp,
                           unsigned int* __restrict__ out) {
  const int which = blockIdx.y;
  const float* w = which ? wp : wa;
  const int n = which ? (NXc * NXc) : (NXc * NQKV);
  float mx = 0.f;
  for (int i = blockIdx.x * blockDim.x + threadIdx.x; i < n;
       i += gridDim.x * blockDim.x)
    mx = fmaxf(mx, fabsf(tanhf(w[i])));
#pragma unroll
  for (int off = 32; off > 0; off >>= 1)
    mx = fmaxf(mx, __shfl_xor(mx, off));
  if ((threadIdx.x & 63) == 0)
    atomicMax(out + which, __float_as_uint(mx));   // floats >= 0: uint order == float order
}

// ---------------- DoReFa weight quant -> transposed exact-bf16 integer weights ----
__global__ __launch_bounds__(256) void k_quantw_t(
    const float* __restrict__ w, unsigned short* __restrict__ ut,
    int K, int N, const unsigned int* __restrict__ gmax_bits) {
  __shared__ unsigned short Ut[64][72];
  const float inv2m = 0.5f / __uint_as_float(*gmax_bits);
  const int k0 = blockIdx.y * 64, n0 = blockIdx.x * 64;
  const int t = threadIdx.x;
  const int r = t >> 4, c4 = (t & 15) * 4;
#pragma unroll
  for (int rr = 0; rr < 4; ++rr) {
    int row = rr * 16 + r;
    float4 f = *(const float4*)(w + (size_t)(k0 + row) * N + n0 + c4);
    float fv[4] = {f.x, f.y, f.z, f.w};
#pragma unroll
    for (int j = 0; j < 4; ++j) {
      float tq = tanhf(fv[j]) * inv2m + 0.5f;
      float u = 2.0f * rintf(tq * 255.0f) - 255.0f;
      Ut[c4 + j][row] = f2bf(u);
    }
  }
  __syncthreads();
#pragma unroll
  for (int rep = 0; rep < 2; ++rep) {
    int c = t + rep * 256;
    int n = c >> 3, slot = c & 7;
    short8 v = *(const short8*)&Ut[n][slot * 8];
    *(short8*)(ut + (size_t)(n0 + n) * K + k0 + slot * 8) = v;
  }
}

// ---------------- x -> hi/lo bf16 split (once; GEMM staging becomes pure copy) ----
__global__ __launch_bounds__(256) void k_split(
    const float* __restrict__ x, unsigned short* __restrict__ xhi,
    unsigned short* __restrict__ xlo, int n8) {
  int i = blockIdx.x * 256 + threadIdx.x;
  if (i >= n8) return;
  const float* src = x + (size_t)i * 8;
  float4 f0 = *(const float4*)src;
  float4 f1 = *(const float4*)(src + 4);
  float fv[8] = {f0.x, f0.y, f0.z, f0.w, f1.x, f1.y, f1.z, f1.w};
  union { short8 v; unsigned short u[8]; } hi, lo;
#pragma unroll
  for (int j = 0; j < 8; ++j) {
    unsigned short hh = f2bf(fv[j]);
    hi.u[j] = hh;
    lo.u[j] = f2bf(fv[j] - bf2f(hh));
  }
  *(short8*)(xhi + (size_t)i * 8) = hi.v;
  *(short8*)(xlo + (size_t)i * 8) = lo.v;
}

// ---------------- MFMA GEMM: C = (A * U^T)/255 + bias ----------------
// SPLIT=1: A given as pre-split hi/lo bf16 arrays, 2 MFMA per frag (exact to ~2^-17).
//          (lo skipped for bn<6 in EPI=1: q-part needs no exactness.)
// SPLIT=0: A single bf16 array, 1 MFMA per frag.
// LDS slot stride 130 (pad +2 entries): staging-write bank quads (2*slot+mr)%8 ->
// exactly 2 lanes/quad per 16-lane phase (free); reads contiguous per phase.
// EPI 0: plain fp32 store. EPI 1: act-quant -> qbf/kbf/vbt (bf16 int) + k/v fp32 out.
#define LSTRIDE 130
template <int EPI, int SPLIT>
__global__ __launch_bounds__(256) void k_gemm_mfma(
    const unsigned short* __restrict__ Ahi_g, const unsigned short* __restrict__ Alo_g,
    const unsigned short* __restrict__ Ut,
    const float* __restrict__ bias, float* __restrict__ Cplain,
    unsigned short* __restrict__ qbf, unsigned short* __restrict__ kbf,
    unsigned short* __restrict__ vbt,
    float* __restrict__ kq, float* __restrict__ vq,
    int M, int N, int K) {
  __shared__ short8 Ahi[4 * LSTRIDE];
  __shared__ short8 Alo[SPLIT ? 4 * LSTRIDE : 4];
  __shared__ short8 Bsm[4 * LSTRIDE];

  const int t = threadIdx.x;
  const int bm = blockIdx.y, bn = blockIdx.x;
  const int wave = t >> 6, lane = t & 63;
  const int wm = wave >> 1, wn = wave & 1;
  const int g = lane >> 4, ln = lane & 15;

  const bool do_lo = SPLIT && !(EPI == 1 && bn < 6);   // q-part: hi only

  const unsigned short* Ahb = Ahi_g + (size_t)bm * 128 * K;
  const unsigned short* Alb = SPLIT ? (Alo_g + (size_t)bm * 128 * K) : (const unsigned short*)0;
  const unsigned short* Bb  = Ut + (size_t)bn * 128 * K;

  f32x4 acc[4][4];
#pragma unroll
  for (int i = 0; i < 4; ++i)
#pragma unroll
    for (int j = 0; j < 4; ++j) acc[i][j] = (f32x4)(0.f);

  for (int k0 = 0; k0 < K; k0 += 32) {
    __syncthreads();
#pragma unroll
    for (int rep = 0; rep < 2; ++rep) {
      int e = t + rep * 256;
      int slot = e & 3, mr = e >> 2;
      size_t goff = (size_t)mr * K + k0 + slot * 8;
      Ahi[slot * LSTRIDE + mr] = *(const short8*)(Ahb + goff);
      if (do_lo) Alo[slot * LSTRIDE + mr] = *(const short8*)(Alb + goff);
      Bsm[slot * LSTRIDE + mr] = *(const short8*)(Bb + goff);
    }
    __syncthreads();

    short8 bfrag[4];
#pragma unroll
    for (int nf = 0; nf < 4; ++nf)
      bfrag[nf] = Bsm[g * LSTRIDE + wn * 64 + nf * 16 + ln];
#pragma unroll
    for (int mf = 0; mf < 4; ++mf) {
      short8 ah = Ahi[g * LSTRIDE + wm * 64 + mf * 16 + ln];
#pragma unroll
      for (int nf = 0; nf < 4; ++nf)
        acc[mf][nf] = __builtin_amdgcn_mfma_f32_16x16x32_bf16(ah, bfrag[nf], acc[mf][nf], 0, 0, 0);
      if (do_lo) {
        short8 al = Alo[g * LSTRIDE + wm * 64 + mf * 16 + ln];
#pragma unroll
        for (int nf = 0; nf < 4; ++nf)
          acc[mf][nf] = __builtin_amdgcn_mfma_f32_16x16x32_bf16(al, bfrag[nf], acc[mf][nf], 0, 0, 0);
      }
    }
  }

  const float inv255 = 1.0f / 255.0f;
#pragma unroll
  for (int mf = 0; mf < 4; ++mf) {
    int row0 = bm * 128 + wm * 64 + mf * 16 + g * 4;
#pragma unroll
    for (int nf = 0; nf < 4; ++nf) {
      int col = bn * 128 + wn * 64 + nf * 16 + ln;
      float bv = bias[col];
#pragma unroll
      for (int r = 0; r < 4; ++r) {
        float x = acc[mf][nf][r] * inv255 + bv;
        int row = row0 + r;
        if (EPI == 0) {
          Cplain[(size_t)row * N + col] = x;
        } else {
          int part = col / NXc;
          int ff = col - part * NXc;
          int h = ff >> 6, d = ff & 63;
          int b = row >> 10, s = row & 1023;
          float y255 = rintf(fminf(fmaxf(x, 0.f), 1.f) * 255.0f);
          unsigned short ybf = f2bf(y255);
          size_t dst = (((size_t)b * H_ + h) * S_ + s) * HDc + d;
          if (part == 0) {
            qbf[dst] = ybf;
          } else if (part == 1) {
            kq[dst] = y255 * inv255;
            kbf[dst] = ybf;
          } else {
            vq[dst] = y255 * inv255;
            vbt[(((size_t)b * H_ + h) * HDc + d) * S_ + s] = ybf;   // transposed
          }
        }
      }
    }
  }
}

// ---------------- MFMA causal flash attention (paired q-blocks) ----------------
// grid (8, H, B), 256 thr (4 waves x 16 q-rows). WG p handles q-blocks {p, 15-p}
// -> exactly 17 kv-tiles per WG (perfect balance). All operands bf16 integers.
// QK^T exact (sums < 2^23). P bf16-only. V read from pre-transposed vbt.
__global__ __launch_bounds__(256) void k_attn_pair(
    const unsigned short* __restrict__ qbf, const unsigned short* __restrict__ kbf,
    const unsigned short* __restrict__ vbt, unsigned short* __restrict__ abf) {
  __shared__ __align__(16) unsigned short Ks[64 * 64];      // [kv][d] ^ ((kv&7)<<3)
  __shared__ __align__(16) unsigned short Vt[64 * 64];      // [d][kv] ^ ((d&7)<<3)
  __shared__ __align__(16) unsigned short Pp[4 * 16 * 64];  // per-wave [q][kv] ^ ((q&7)<<3)

  const int p = blockIdx.x, h = blockIdx.y, b = blockIdx.z;
  const size_t hoff = ((size_t)(b * H_ + h)) * S_ * HDc;  // same elem count for [s][d] and [d][s]
  const unsigned short* qh = qbf + hoff;
  const unsigned short* kh = kbf + hoff;
  const unsigned short* vh = vbt + hoff;

  const int t = threadIdx.x;
  const int w = t >> 6, lane = t & 63;
  const int g = lane >> 4, ln = lane & 15;

  const float SCALE = 1.0f / (255.0f * 255.0f * 8.0f);

  for (int ph = 0; ph < 2; ++ph) {
    const int iq = ph ? 15 - p : p;

    // Q fragments: rows iq*64 + w*16 + ln (integer-scaled bf16)
    const unsigned short* qr = qh + (size_t)(iq * 64 + w * 16 + ln) * HDc;
    short8 qfrag[2];
    qfrag[0] = *(const short8*)(qr + g * 8);
    qfrag[1] = *(const short8*)(qr + 32 + g * 8);

    float m[4], l[4];
    f32x4 accO[4];
#pragma unroll
    for (int r = 0; r < 4; ++r) { m[r] = -1e30f; l[r] = 0.f; }
#pragma unroll
    for (int nf = 0; nf < 4; ++nf) accO[nf] = (f32x4)(0.f);

    for (int jb = 0; jb <= iq; ++jb) {
      __syncthreads();   // previous tile's LDS reads complete
#pragma unroll
      for (int rep = 0; rep < 2; ++rep) {
        int e = t + rep * 256;
        int row = e >> 3, slot = e & 7;
        short8 kk = *(const short8*)(kh + (size_t)(jb * 64 + row) * HDc + slot * 8);
        *(short8*)&Ks[row * 64 + ((slot * 8) ^ ((row & 7) << 3))] = kk;
        short8 vv = *(const short8*)(vh + (size_t)row * S_ + jb * 64 + slot * 8);
        *(short8*)&Vt[row * 64 + ((slot * 8) ^ ((row & 7) << 3))] = vv;
      }
      __syncthreads();

      // QK^T (exact integer)
      f32x4 accS[4];
#pragma unroll
      for (int nf = 0; nf < 4; ++nf) accS[nf] = (f32x4)(0.f);
#pragma unroll
      for (int ks = 0; ks < 2; ++ks)
#pragma unroll
        for (int nf = 0; nf < 4; ++nf) {
          int kvr = nf * 16 + ln;
          short8 bk = *(const short8*)&Ks[kvr * 64 + ((ks * 32 + g * 8) ^ ((kvr & 7) << 3))];
          accS[nf] = __builtin_amdgcn_mfma_f32_16x16x32_bf16(qfrag[ks], bk, accS[nf], 0, 0, 0);
        }

      // scale + causal mask (rows g*4+r, cols nf*16+ln)
      float sv[4][4];
      if (jb == iq) {
        const int grow = iq * 64 + w * 16 + g * 4;
        const int gcol = jb * 64 + ln;
#pragma unroll
        for (int nf = 0; nf < 4; ++nf)
#pragma unroll
          for (int r = 0; r < 4; ++r)
            sv[nf][r] = (gcol + nf * 16 > grow + r) ? -1e30f : accS[nf][r] * SCALE;
      } else {
#pragma unroll
        for (int nf = 0; nf < 4; ++nf)
#pragma unroll
          for (int r = 0; r < 4; ++r) sv[nf][r] = accS[nf][r] * SCALE;
      }

      // online softmax (rows g*4+r shared by the 16 ln-lanes)
      float mt[4];
#pragma unroll
      for (int r = 0; r < 4; ++r)
        mt[r] = fmaxf(fmaxf(sv[0][r], sv[1][r]), fmaxf(sv[2][r], sv[3][r]));
#pragma unroll
      for (int off = 1; off < 16; off <<= 1)
#pragma unroll
        for (int r = 0; r < 4; ++r) mt[r] = fmaxf(mt[r], __shfl_xor(mt[r], off));

      float pr[4][4], rs[4];
#pragma unroll
      for (int r = 0; r < 4; ++r) {
        float mn = fmaxf(m[r], mt[r]);
        float corr = __expf(m[r] - mn);
        m[r] = mn;
        l[r] *= corr;
#pragma unroll
        for (int nf = 0; nf < 4; ++nf) accO[nf][r] *= corr;
        float sum = 0.f;
#pragma unroll
        for (int nf = 0; nf < 4; ++nf) {
          float pv = __expf(sv[nf][r] - mn);
          pr[nf][r] = pv;
          sum += pv;
        }
        rs[r] = sum;
      }
#pragma unroll
      for (int off = 1; off < 16; off <<= 1)
#pragma unroll
        for (int r = 0; r < 4; ++r) rs[r] += __shfl_xor(rs[r], off);
#pragma unroll
      for (int r = 0; r < 4; ++r) l[r] += rs[r];

      // P -> LDS (bf16, within-wave round trip, no barrier)
#pragma unroll
      for (int nf = 0; nf < 4; ++nf)
#pragma unroll
        for (int r = 0; r < 4; ++r) {
          int prow = g * 4 + r;
          Pp[w * 1024 + prow * 64 + ((nf * 16 + ln) ^ ((prow & 7) << 3))] = f2bf(pr[nf][r]);
        }

      // PV: accO[nf] += P(16x32) * V(32x16)
#pragma unroll
      for (int ks = 0; ks < 2; ++ks) {
        short8 pa = *(const short8*)&Pp[w * 1024 + ln * 64 + ((ks * 32 + g * 8) ^ ((ln & 7) << 3))];
#pragma unroll
        for (int nf = 0; nf < 4; ++nf) {
          int d = nf * 16 + ln;
          short8 bv = *(const short8*)&Vt[d * 64 + ((ks * 32 + g * 8) ^ ((d & 7) << 3))];
          accO[nf] = __builtin_amdgcn_mfma_f32_16x16x32_bf16(pa, bv, accO[nf], 0, 0, 0);
        }
      }
    }

    // write attn-out bf16 [B,S,NX]; accO rows q=g*4+r, cols d=nf*16+ln; V scaled x255
#pragma unroll
    for (int r = 0; r < 4; ++r) {
      float inv = 1.0f / (255.0f * l[r]);
      size_t row = (size_t)b * S_ + iq * 64 + w * 16 + g * 4 + r;
#pragma unroll
      for (int nf = 0; nf < 4; ++nf)
        abf[row * NXc + h * HDc + nf * 16 + ln] = f2bf(accO[nf][r] * inv);
    }
  }
}

// ---------------- host launcher ----------------
extern "C" void kernel_launch(void* const* d_in, const int* in_sizes, int n_in,
                              void* d_out, int out_size, void* d_ws, size_t ws_size,
                              hipStream_t stream) {
  const float* x      = (const float*)d_in[0];
  const float* W_attn = (const float*)d_in[1];
  const float* b_attn = (const float*)d_in[2];
  const float* W_proj = (const float*)d_in[3];
  const float* b_proj = (const float*)d_in[4];

  float* out = (float*)d_out;
  float* ws  = (float*)d_ws;
  if (ws_size < WS_FLOATS_NEEDED * sizeof(float)) return;

  float* a_out = out;                               // [B,S,NX]
  float* k_out = out + (size_t)M_ * NXc;            // present[0] = k  [B,H,S,hd]
  float* v_out = k_out + (size_t)M_ * NXc;          // present[1] = v

  unsigned short* ua  = (unsigned short*)(ws + UA_OFF_F);
  unsigned short* up  = (unsigned short*)(ws + UP_OFF_F);
  unsigned short* qbf = (unsigned short*)(ws + QBF_OFF_F);
  unsigned short* kbf = (unsigned short*)(ws + KBF_OFF_F);
  unsigned short* vbt = (unsigned short*)(ws + VBT_OFF_F);
  unsigned short* abf = (unsigned short*)(ws + ABF_OFF_F);
  unsigned int* sc = (unsigned int*)(ws + SC_OFF);

  // region reuse (stream-serial, all fully rewritten before their real use):
  //   xhi lives in abf's slot (attn writes abf only AFTER qkv GEMM consumed xhi)
  //   xlo lives in a_out (proj writes a_out only AFTER qkv GEMM consumed xlo)
  unsigned short* xhi = abf;
  unsigned short* xlo = (unsigned short*)a_out;

  hipMemsetAsync(sc, 0, 2 * sizeof(unsigned int), stream);

  k_maxtanh2<<<dim3(128, 2), 256, 0, stream>>>(W_attn, W_proj, sc);

  k_quantw_t<<<dim3(NQKV / 64, NXc / 64), 256, 0, stream>>>(W_attn, ua, NXc, NQKV, sc);
  k_quantw_t<<<dim3(NXc / 64, NXc / 64), 256, 0, stream>>>(W_proj, up, NXc, NXc, sc + 1);

  // x -> hi/lo bf16 (once)
  k_split<<<(M_ * NXc / 8 + 255) / 256, 256, 0, stream>>>(x, xhi, xlo, M_ * NXc / 8);

  // qkv = x @ wq_attn + b_attn (pre-split bf16 MFMA); emits bf16 q,k,v^T + fp32 present
  k_gemm_mfma<1, 1><<<dim3(NQKV / 128, M_ / 128), 256, 0, stream>>>(
      xhi, xlo, ua, b_attn, nullptr, qbf, kbf, vbt, k_out, v_out, M_, NQKV, NXc);

  // causal attention (paired q-blocks, all-bf16) — overwrites xhi region with abf
  k_attn_pair<<<dim3(8, H_, B_), 256, 0, stream>>>(qbf, kbf, vbt, abf);

  // a = attn_out @ wq_proj + b_proj (bf16 A, single MFMA) — overwrites xlo region
  k_gemm_mfma<0, 0><<<dim3(NXc / 128, M_ / 128), 256, 0, stream>>>(
      abf, nullptr, up, b_proj, a_out, nullptr, nullptr, nullptr, nullptr, nullptr,
      M_, NXc, NXc);
}

// Round 6
// 211.254 us; speedup vs baseline: 1.1675x; 1.1675x over previous
//
#include <hip/hip_runtime.h>
#include <math.h>

#define B_   8
#define S_   1024
#define NXc  768
#define H_   12
#define HDc  64
#define M_   (B_*S_)        // 8192
#define NQKV (3*NXc)        // 2304

typedef __attribute__((ext_vector_type(8))) short short8;
typedef __attribute__((ext_vector_type(4))) float f32x4;

__device__ inline unsigned short f2bf(float f) {
  unsigned u = __float_as_uint(f);
  return (unsigned short)((u + 0x7fffu + ((u >> 16) & 1u)) >> 16);
}
__device__ inline float bf2f(unsigned short h) {
  return __uint_as_float(((unsigned)h) << 16);
}
__device__ inline void gl_lds16(const unsigned short* g, unsigned short* l) {
  __builtin_amdgcn_global_load_lds(
      (const __attribute__((address_space(1))) void*)g,
      (__attribute__((address_space(3))) void*)l, 16, 0, 0);
}

// ---- workspace layout (floats) ----
static const size_t UA_OFF_F  = 0;                                   // bf16 Ut attn [NQKV][NXc]
static const size_t UA_F_CNT  = ((size_t)NQKV * NXc + 1) / 2;        // 884736
static const size_t UP_OFF_F  = UA_OFF_F + UA_F_CNT;                 // bf16 Ut proj [NXc][NXc]
static const size_t UP_F_CNT  = ((size_t)NXc * NXc + 1) / 2;         // 294912
static const size_t QBF_OFF_F = UP_OFF_F + UP_F_CNT;                 // bf16 int q [B,H,S,64]
static const size_t HALF_CNT  = ((size_t)M_ * NXc + 1) / 2;          // 3145728
static const size_t KBF_OFF_F = QBF_OFF_F + HALF_CNT;                // bf16 int k [B,H,S,64]
static const size_t VBT_OFF_F = KBF_OFF_F + HALF_CNT;                // bf16 int v^T [B,H,64,S]
static const size_t ABF_OFF_F = VBT_OFF_F + HALF_CNT;                // bf16 attn out [B,S,NX]
                                                                     // (ALSO: xhi before attn)
static const size_t SC_OFF    = ABF_OFF_F + HALF_CNT;
static const size_t WS_FLOATS_NEEDED = SC_OFF + 2;                   // ~13.8M floats (55MB)

// ---------------- max |tanh(w)| reduction, both weights in one launch --------
__global__ void k_maxtanh2(const float* __restrict__ wa, const float* __restrict__ wp,
                           unsigned int* __restrict__ out) {
  const int which = blockIdx.y;
  const float* w = which ? wp : wa;
  const int n = which ? (NXc * NXc) : (NXc * NQKV);
  float mx = 0.f;
  for (int i = blockIdx.x * blockDim.x + threadIdx.x; i < n;
       i += gridDim.x * blockDim.x)
    mx = fmaxf(mx, fabsf(tanhf(w[i])));
#pragma unroll
  for (int off = 32; off > 0; off >>= 1)
    mx = fmaxf(mx, __shfl_xor(mx, off));
  if ((threadIdx.x & 63) == 0)
    atomicMax(out + which, __float_as_uint(mx));   // floats >= 0: uint order == float order
}

// ---------------- DoReFa weight quant -> transposed exact-bf16 integer weights ----
__global__ __launch_bounds__(256) void k_quantw_t(
    const float* __restrict__ w, unsigned short* __restrict__ ut,
    int K, int N, const unsigned int* __restrict__ gmax_bits) {
  __shared__ unsigned short Ut[64][72];
  const float inv2m = 0.5f / __uint_as_float(*gmax_bits);
  const int k0 = blockIdx.y * 64, n0 = blockIdx.x * 64;
  const int t = threadIdx.x;
  const int r = t >> 4, c4 = (t & 15) * 4;
#pragma unroll
  for (int rr = 0; rr < 4; ++rr) {
    int row = rr * 16 + r;
    float4 f = *(const float4*)(w + (size_t)(k0 + row) * N + n0 + c4);
    float fv[4] = {f.x, f.y, f.z, f.w};
#pragma unroll
    for (int j = 0; j < 4; ++j) {
      float tq = tanhf(fv[j]) * inv2m + 0.5f;
      float u = 2.0f * rintf(tq * 255.0f) - 255.0f;
      Ut[c4 + j][row] = f2bf(u);
    }
  }
  __syncthreads();
#pragma unroll
  for (int rep = 0; rep < 2; ++rep) {
    int c = t + rep * 256;
    int n = c >> 3, slot = c & 7;
    short8 v = *(const short8*)&Ut[n][slot * 8];
    *(short8*)(ut + (size_t)(n0 + n) * K + k0 + slot * 8) = v;
  }
}

// ---------------- x -> hi/lo bf16 split (once) ----------------
__global__ __launch_bounds__(256) void k_split(
    const float* __restrict__ x, unsigned short* __restrict__ xhi,
    unsigned short* __restrict__ xlo, int n8) {
  int i = blockIdx.x * 256 + threadIdx.x;
  if (i >= n8) return;
  const float* src = x + (size_t)i * 8;
  float4 f0 = *(const float4*)src;
  float4 f1 = *(const float4*)(src + 4);
  float fv[8] = {f0.x, f0.y, f0.z, f0.w, f1.x, f1.y, f1.z, f1.w};
  union { short8 v; unsigned short u[8]; } hi, lo;
#pragma unroll
  for (int j = 0; j < 8; ++j) {
    unsigned short hh = f2bf(fv[j]);
    hi.u[j] = hh;
    lo.u[j] = f2bf(fv[j] - bf2f(hh));
  }
  *(short8*)(xhi + (size_t)i * 8) = hi.v;
  *(short8*)(xlo + (size_t)i * 8) = lo.v;
}

// ---------------- MFMA GEMM (m97 structure): C = (A * U^T)/255 + bias ----------
// global_load_lds(16B) staging: LDS linear dest, inverse-XOR-swizzled per-lane
// global source, XOR on read (both-sides rule). BK=64, 128x128 tile, 4 waves.
// LDS layout: T[row][j*8..j*8+7] holds A[row][k0 + (j^(row&7))*8 ...]  (row&7==ln&7
// for frag rows -> read addr row*64 + ((ks*4+g)^(ln&7))*8, 2-way aliasing = free).
// XCD swizzle: same-bm blocks pinned to one XCD (nblk % 8 == 0).
// SPLIT=1: hi+lo MFMA (lo skipped for q columns bn<6 when EPI=1). SPLIT=0: hi only.
template <int EPI, int SPLIT>
__global__ __launch_bounds__(256) void k_gemm2(
    const unsigned short* __restrict__ Ahi_g, const unsigned short* __restrict__ Alo_g,
    const unsigned short* __restrict__ Ut,
    const float* __restrict__ bias, float* __restrict__ Cplain,
    unsigned short* __restrict__ qbf, unsigned short* __restrict__ kbf,
    unsigned short* __restrict__ vbt,
    float* __restrict__ kq, float* __restrict__ vq,
    int M, int N, int K, int nbn) {
  __shared__ __align__(16) unsigned short Ah[128 * 64];
  __shared__ __align__(16) unsigned short Al[SPLIT ? 128 * 64 : 8];
  __shared__ __align__(16) unsigned short Bs[128 * 64];

  const int nblk = gridDim.x;
  const int cpx = nblk >> 3;
  const int bid = blockIdx.x;
  const int swz = (bid & 7) * cpx + (bid >> 3);
  const int bm = swz / nbn, bn = swz % nbn;

  const int t = threadIdx.x;
  const int w = t >> 6, lane = t & 63;
  const int wm = w >> 1, wn = w & 1;
  const int g = lane >> 4, ln = lane & 15;

  const bool do_lo = SPLIT && !(EPI == 1 && bn < 6);   // q-part: hi only

  const unsigned short* Ahb = Ahi_g + (size_t)bm * 128 * K;
  const unsigned short* Alb = SPLIT ? (Alo_g + (size_t)bm * 128 * K) : (const unsigned short*)0;
  const unsigned short* Bb  = Ut + (size_t)bn * 128 * K;

  f32x4 acc[4][4];
#pragma unroll
  for (int i = 0; i < 4; ++i)
#pragma unroll
    for (int j = 0; j < 4; ++j) acc[i][j] = (f32x4)(0.f);

  // staging geometry: slot s in [0,1024): row=s>>3, chunk=s&7 (8x16B per row)
  const int srow = (w * 64 + lane) >> 3;        // rep adds 32 rows
  const int schunk = lane & 7;
  for (int k0 = 0; k0 < K; k0 += 64) {
    __syncthreads();   // prior tile's LDS reads done
#pragma unroll
    for (int rep = 0; rep < 4; ++rep) {
      const int sb = rep * 256 + w * 64;        // wave-uniform slot base
      const int r = srow + rep * 32;
      const size_t goff = (size_t)r * K + k0 + ((schunk ^ (r & 7)) << 3);
      gl_lds16(Ahb + goff, &Ah[(size_t)sb * 8]);
      if (do_lo) gl_lds16(Alb + goff, &Al[(size_t)sb * 8]);
      gl_lds16(Bb + goff, &Bs[(size_t)sb * 8]);
    }
    __syncthreads();   // vmcnt(0) drain -> LDS valid

#pragma unroll
    for (int ks = 0; ks < 2; ++ks) {
      const int jx = ((((ks << 2) + g) ^ (ln & 7)) << 3);
      short8 bfrag[4];
#pragma unroll
      for (int nf = 0; nf < 4; ++nf)
        bfrag[nf] = *(const short8*)&Bs[(wn * 64 + nf * 16 + ln) * 64 + jx];
#pragma unroll
      for (int mf = 0; mf < 4; ++mf) {
        short8 ah = *(const short8*)&Ah[(wm * 64 + mf * 16 + ln) * 64 + jx];
#pragma unroll
        for (int nf = 0; nf < 4; ++nf)
          acc[mf][nf] = __builtin_amdgcn_mfma_f32_16x16x32_bf16(ah, bfrag[nf], acc[mf][nf], 0, 0, 0);
      }
      if (do_lo) {
#pragma unroll
        for (int mf = 0; mf < 4; ++mf) {
          short8 al = *(const short8*)&Al[(wm * 64 + mf * 16 + ln) * 64 + jx];
#pragma unroll
          for (int nf = 0; nf < 4; ++nf)
            acc[mf][nf] = __builtin_amdgcn_mfma_f32_16x16x32_bf16(al, bfrag[nf], acc[mf][nf], 0, 0, 0);
        }
      }
    }
  }

  const float inv255 = 1.0f / 255.0f;
#pragma unroll
  for (int mf = 0; mf < 4; ++mf) {
    int row0 = bm * 128 + wm * 64 + mf * 16 + g * 4;
#pragma unroll
    for (int nf = 0; nf < 4; ++nf) {
      int col = bn * 128 + wn * 64 + nf * 16 + ln;
      float bv = bias[col];
#pragma unroll
      for (int r = 0; r < 4; ++r) {
        float x = acc[mf][nf][r] * inv255 + bv;
        int row = row0 + r;
        if (EPI == 0) {
          Cplain[(size_t)row * N + col] = x;
        } else {
          int part = col / NXc;
          int ff = col - part * NXc;
          int h = ff >> 6, d = ff & 63;
          int b = row >> 10, s = row & 1023;
          float y255 = rintf(fminf(fmaxf(x, 0.f), 1.f) * 255.0f);
          unsigned short ybf = f2bf(y255);
          size_t dst = (((size_t)b * H_ + h) * S_ + s) * HDc + d;
          if (part == 0) {
            qbf[dst] = ybf;
          } else if (part == 1) {
            kq[dst] = y255 * inv255;
            kbf[dst] = ybf;
          } else {
            vq[dst] = y255 * inv255;
            vbt[(((size_t)b * H_ + h) * HDc + d) * S_ + s] = ybf;   // transposed
          }
        }
      }
    }
  }
}

// ---------------- MFMA causal flash attention (paired q-blocks) ----------------
// grid (8, H, B), 256 thr (4 waves x 16 q-rows). WG p handles q-blocks {p, 15-p}
// -> exactly 17 kv-tiles per WG (perfect balance). All operands bf16 integers.
// QK^T exact (sums < 2^23). P bf16-only. V read from pre-transposed vbt.
__global__ __launch_bounds__(256) void k_attn_pair(
    const unsigned short* __restrict__ qbf, const unsigned short* __restrict__ kbf,
    const unsigned short* __restrict__ vbt, unsigned short* __restrict__ abf) {
  __shared__ __align__(16) unsigned short Ks[64 * 64];      // [kv][d] ^ ((kv&7)<<3)
  __shared__ __align__(16) unsigned short Vt[64 * 64];      // [d][kv] ^ ((d&7)<<3)
  __shared__ __align__(16) unsigned short Pp[4 * 16 * 64];  // per-wave [q][kv] ^ ((q&7)<<3)

  const int p = blockIdx.x, h = blockIdx.y, b = blockIdx.z;
  const size_t hoff = ((size_t)(b * H_ + h)) * S_ * HDc;  // same elem count for [s][d] and [d][s]
  const unsigned short* qh = qbf + hoff;
  const unsigned short* kh = kbf + hoff;
  const unsigned short* vh = vbt + hoff;

  const int t = threadIdx.x;
  const int w = t >> 6, lane = t & 63;
  const int g = lane >> 4, ln = lane & 15;

  const float SCALE = 1.0f / (255.0f * 255.0f * 8.0f);

  for (int ph = 0; ph < 2; ++ph) {
    const int iq = ph ? 15 - p : p;

    // Q fragments: rows iq*64 + w*16 + ln (integer-scaled bf16)
    const unsigned short* qr = qh + (size_t)(iq * 64 + w * 16 + ln) * HDc;
    short8 qfrag[2];
    qfrag[0] = *(const short8*)(qr + g * 8);
    qfrag[1] = *(const short8*)(qr + 32 + g * 8);

    float m[4], l[4];
    f32x4 accO[4];
#pragma unroll
    for (int r = 0; r < 4; ++r) { m[r] = -1e30f; l[r] = 0.f; }
#pragma unroll
    for (int nf = 0; nf < 4; ++nf) accO[nf] = (f32x4)(0.f);

    for (int jb = 0; jb <= iq; ++jb) {
      __syncthreads();   // previous tile's LDS reads complete
#pragma unroll
      for (int rep = 0; rep < 2; ++rep) {
        int e = t + rep * 256;
        int row = e >> 3, slot = e & 7;
        short8 kk = *(const short8*)(kh + (size_t)(jb * 64 + row) * HDc + slot * 8);
        *(short8*)&Ks[row * 64 + ((slot * 8) ^ ((row & 7) << 3))] = kk;
        short8 vv = *(const short8*)(vh + (size_t)row * S_ + jb * 64 + slot * 8);
        *(short8*)&Vt[row * 64 + ((slot * 8) ^ ((row & 7) << 3))] = vv;
      }
      __syncthreads();

      // QK^T (exact integer)
      f32x4 accS[4];
#pragma unroll
      for (int nf = 0; nf < 4; ++nf) accS[nf] = (f32x4)(0.f);
#pragma unroll
      for (int ks = 0; ks < 2; ++ks)
#pragma unroll
        for (int nf = 0; nf < 4; ++nf) {
          int kvr = nf * 16 + ln;
          short8 bk = *(const short8*)&Ks[kvr * 64 + ((ks * 32 + g * 8) ^ ((kvr & 7) << 3))];
          accS[nf] = __builtin_amdgcn_mfma_f32_16x16x32_bf16(qfrag[ks], bk, accS[nf], 0, 0, 0);
        }

      // scale + causal mask (rows g*4+r, cols nf*16+ln)
      float sv[4][4];
      if (jb == iq) {
        const int grow = iq * 64 + w * 16 + g * 4;
        const int gcol = jb * 64 + ln;
#pragma unroll
        for (int nf = 0; nf < 4; ++nf)
#pragma unroll
          for (int r = 0; r < 4; ++r)
            sv[nf][r] = (gcol + nf * 16 > grow + r) ? -1e30f : accS[nf][r] * SCALE;
      } else {
#pragma unroll
        for (int nf = 0; nf < 4; ++nf)
#pragma unroll
          for (int r = 0; r < 4; ++r) sv[nf][r] = accS[nf][r] * SCALE;
      }

      // online softmax (rows g*4+r shared by the 16 ln-lanes)
      float mt[4];
#pragma unroll
      for (int r = 0; r < 4; ++r)
        mt[r] = fmaxf(fmaxf(sv[0][r], sv[1][r]), fmaxf(sv[2][r], sv[3][r]));
#pragma unroll
      for (int off = 1; off < 16; off <<= 1)
#pragma unroll
        for (int r = 0; r < 4; ++r) mt[r] = fmaxf(mt[r], __shfl_xor(mt[r], off));

      float pr[4][4], rs[4];
#pragma unroll
      for (int r = 0; r < 4; ++r) {
        float mn = fmaxf(m[r], mt[r]);
        float corr = __expf(m[r] - mn);
        m[r] = mn;
        l[r] *= corr;
#pragma unroll
        for (int nf = 0; nf < 4; ++nf) accO[nf][r] *= corr;
        float sum = 0.f;
#pragma unroll
        for (int nf = 0; nf < 4; ++nf) {
          float pv = __expf(sv[nf][r] - mn);
          pr[nf][r] = pv;
          sum += pv;
        }
        rs[r] = sum;
      }
#pragma unroll
      for (int off = 1; off < 16; off <<= 1)
#pragma unroll
        for (int r = 0; r < 4; ++r) rs[r] += __shfl_xor(rs[r], off);
#pragma unroll
      for (int r = 0; r < 4; ++r) l[r] += rs[r];

      // P -> LDS (bf16, within-wave round trip, no barrier)
#pragma unroll
      for (int nf = 0; nf < 4; ++nf)
#pragma unroll
        for (int r = 0; r < 4; ++r) {
          int prow = g * 4 + r;
          Pp[w * 1024 + prow * 64 + ((nf * 16 + ln) ^ ((prow & 7) << 3))] = f2bf(pr[nf][r]);
        }

      // PV: accO[nf] += P(16x32) * V(32x16)
#pragma unroll
      for (int ks = 0; ks < 2; ++ks) {
        short8 pa = *(const short8*)&Pp[w * 1024 + ln * 64 + ((ks * 32 + g * 8) ^ ((ln & 7) << 3))];
#pragma unroll
        for (int nf = 0; nf < 4; ++nf) {
          int d = nf * 16 + ln;
          short8 bv = *(const short8*)&Vt[d * 64 + ((ks * 32 + g * 8) ^ ((d & 7) << 3))];
          accO[nf] = __builtin_amdgcn_mfma_f32_16x16x32_bf16(pa, bv, accO[nf], 0, 0, 0);
        }
      }
    }

    // write attn-out bf16 [B,S,NX]; accO rows q=g*4+r, cols d=nf*16+ln; V scaled x255
#pragma unroll
    for (int r = 0; r < 4; ++r) {
      float inv = 1.0f / (255.0f * l[r]);
      size_t row = (size_t)b * S_ + iq * 64 + w * 16 + g * 4 + r;
#pragma unroll
      for (int nf = 0; nf < 4; ++nf)
        abf[row * NXc + h * HDc + nf * 16 + ln] = f2bf(accO[nf][r] * inv);
    }
  }
}

// ---------------- host launcher ----------------
extern "C" void kernel_launch(void* const* d_in, const int* in_sizes, int n_in,
                              void* d_out, int out_size, void* d_ws, size_t ws_size,
                              hipStream_t stream) {
  const float* x      = (const float*)d_in[0];
  const float* W_attn = (const float*)d_in[1];
  const float* b_attn = (const float*)d_in[2];
  const float* W_proj = (const float*)d_in[3];
  const float* b_proj = (const float*)d_in[4];

  float* out = (float*)d_out;
  float* ws  = (float*)d_ws;
  if (ws_size < WS_FLOATS_NEEDED * sizeof(float)) return;

  float* a_out = out;                               // [B,S,NX]
  float* k_out = out + (size_t)M_ * NXc;            // present[0] = k  [B,H,S,hd]
  float* v_out = k_out + (size_t)M_ * NXc;          // present[1] = v

  unsigned short* ua  = (unsigned short*)(ws + UA_OFF_F);
  unsigned short* up  = (unsigned short*)(ws + UP_OFF_F);
  unsigned short* qbf = (unsigned short*)(ws + QBF_OFF_F);
  unsigned short* kbf = (unsigned short*)(ws + KBF_OFF_F);
  unsigned short* vbt = (unsigned short*)(ws + VBT_OFF_F);
  unsigned short* abf = (unsigned short*)(ws + ABF_OFF_F);
  unsigned int* sc = (unsigned int*)(ws + SC_OFF);

  // region reuse (stream-serial, all fully rewritten before their real use):
  //   xhi lives in abf's slot (attn writes abf only AFTER qkv GEMM consumed xhi)
  //   xlo lives in a_out (proj writes a_out only AFTER qkv GEMM consumed xlo)
  unsigned short* xhi = abf;
  unsigned short* xlo = (unsigned short*)a_out;

  hipMemsetAsync(sc, 0, 2 * sizeof(unsigned int), stream);

  k_maxtanh2<<<dim3(128, 2), 256, 0, stream>>>(W_attn, W_proj, sc);

  k_quantw_t<<<dim3(NQKV / 64, NXc / 64), 256, 0, stream>>>(W_attn, ua, NXc, NQKV, sc);
  k_quantw_t<<<dim3(NXc / 64, NXc / 64), 256, 0, stream>>>(W_proj, up, NXc, NXc, sc + 1);

  // x -> hi/lo bf16 (once)
  k_split<<<(M_ * NXc / 8 + 255) / 256, 256, 0, stream>>>(x, xhi, xlo, M_ * NXc / 8);

  // qkv = x @ wq_attn + b_attn; emits bf16 q,k,v^T + fp32 present
  k_gemm2<1, 1><<<(NQKV / 128) * (M_ / 128), 256, 0, stream>>>(
      xhi, xlo, ua, b_attn, nullptr, qbf, kbf, vbt, k_out, v_out,
      M_, NQKV, NXc, NQKV / 128);

  // causal attention (paired q-blocks, all-bf16) — overwrites xhi region with abf
  k_attn_pair<<<dim3(8, H_, B_), 256, 0, stream>>>(qbf, kbf, vbt, abf);

  // a = attn_out @ wq_proj + b_proj (bf16 A, single MFMA) — overwrites xlo region
  k_gemm2<0, 0><<<(NXc / 128) * (M_ / 128), 256, 0, stream>>>(
      abf, nullptr, up, b_proj, a_out, nullptr, nullptr, nullptr, nullptr, nullptr,
      M_, NXc, NXc, NXc / 128);
}